// Round 3
// baseline (464.728 us; speedup 1.0000x reference)
//
#include <hip/hip_runtime.h>
#include <math.h>

#define Bq 16
#define Mq 2048
#define Hq 1024
static constexpr float THR = 0.99f;

// ---------------------------------------------------------------------------
// K0: per-batch live-token count (nlive[b] = sum(run[b,:]))
// ---------------------------------------------------------------------------
__global__ __launch_bounds__(256) void k_count(const int* __restrict__ run,
                                               int* __restrict__ nlive) {
  int b = blockIdx.x;
  int tid = threadIdx.x;
  int s = 0;
  const int* r = run + b * Mq;
  for (int m = tid; m < Mq; m += 256) s += r[m];
#pragma unroll
  for (int off = 32; off; off >>= 1) s += __shfl_xor(s, off);
  __shared__ int ws4[4];
  if ((tid & 63) == 0) ws4[tid >> 6] = s;
  __syncthreads();
  if (tid == 0) nlive[b] = ws4[0] + ws4[1] + ws4[2] + ws4[3];
}

// ---------------------------------------------------------------------------
// K1: GEMV logits[b,r] = dot(h[b,r,:], p_weight) + p_bias for r < nlive[b]
// one wave per row, 4 rows per 256-thread block; only live-packed rows read.
// ---------------------------------------------------------------------------
__global__ __launch_bounds__(256) void k_gemv(const float* __restrict__ h,
                                              const float* __restrict__ pw,
                                              const float* __restrict__ pb,
                                              const int* __restrict__ nlive,
                                              float* __restrict__ logits) {
  int wv = threadIdx.x >> 6, lane = threadIdx.x & 63;
  int b = blockIdx.x >> 9;                      // 512 blocks per batch row
  int r = ((blockIdx.x & 511) << 2) + wv;
  if (r >= nlive[b]) return;
  const float4* hrow = (const float4*)(h + ((size_t)(b * Mq + r)) * Hq);
  const float4* w4 = (const float4*)pw;
  float s = 0.f;
#pragma unroll
  for (int k = 0; k < 4; ++k) {
    int i = (k << 6) + lane;                    // coalesced: lane-contiguous
    float4 a = hrow[i], w = w4[i];
    s += a.x * w.x + a.y * w.y + a.z * w.z + a.w * w.w;
  }
#pragma unroll
  for (int off = 32; off; off >>= 1) s += __shfl_xor(s, off);
  if (lane == 0) logits[b * Mq + r] = s + pb[0];
}

// ---------------------------------------------------------------------------
// K2: per-row prefix scans + all width-1 outputs + index tables.
// One block per batch row; 8 chunks of 256; wave-scan + LDS wave-sum combine.
// Per slot m:
//   rank_ws  = unpack source rank (-1 if dead)
//   peff_ws  = p_eff (reference arithmetic: exit -> 1-(accn-p))
//   pdest_ws = cdest >= 0    : continuing -> write h-row to packed col cdest
//              -(zd+1) < 0   : otherwise  -> zero-fill packed col zd
//   (cdest over cont slots covers [0,nnew); zd over the rest covers [nnew,M))
// ---------------------------------------------------------------------------
__device__ __forceinline__ int wave_scan(int v, int lane) {
#pragma unroll
  for (int off = 1; off < 64; off <<= 1) {
    int n = __shfl_up(v, off);
    if (lane >= off) v += n;
  }
  return v;
}

__global__ __launch_bounds__(256) void k_scan(
    const float* __restrict__ accp, const float* __restrict__ rem,
    const int* __restrict__ run, const int* __restrict__ exin,
    const int* __restrict__ upd, const float* __restrict__ logits,
    float* __restrict__ out_acc, float* __restrict__ out_rem,
    float* __restrict__ out_run, float* __restrict__ out_exit,
    int* __restrict__ rank_ws, float* __restrict__ peff_ws,
    int* __restrict__ pdest_ws) {
  int b = blockIdx.x;
  int tid = threadIdx.x;
  int lane = tid & 63, wv = tid >> 6;
  __shared__ int wsA[4], wsB[4];
  int carry_run = 0, carry_cont = 0;
  int unew = upd[0] + 1;
  for (int chunk = 0; chunk < Mq; chunk += 256) {
    int m = chunk + tid;
    int idx = b * Mq + m;
    int r = run[idx];
    // --- scan of run -> unpack source rank ---
    int incl = wave_scan(r, lane);
    if (lane == 63) wsA[wv] = incl;
    __syncthreads();
    int pre = 0, tot = 0;
#pragma unroll
    for (int i = 0; i < 4; ++i) { int t = wsA[i]; if (i < wv) pre += t; tot += t; }
    incl += pre;
    int rank = carry_run + incl - 1;            // valid only when r
    // --- per-slot math ---
    float p = 0.f;
    if (r) {
      float z = logits[b * Mq + rank];
      if (z >= 0.f) p = 1.f / (1.f + expf(-z));      // stable sigmoid,
      else { float e = expf(z); p = e / (1.f + e); } // matches jax.nn.sigmoid
    }
    float accn = accp[idx] + p;
    int cont = (int)(accn < THR) & r;
    int ex = r & (cont ^ 1);
    float diff = accn - p;                      // keep reference rounding
    float peff = cont ? p : (ex ? (1.0f - diff) : 0.0f);
    out_acc[idx] = accn;
    out_rem[idx] = rem[idx] + (ex ? peff : 0.0f);
    out_run[idx] = cont ? 1.0f : 0.0f;
    out_exit[idx] = (float)(exin[idx] + (ex ? unew : 0));
    rank_ws[idx] = r ? rank : -1;
    peff_ws[idx] = peff;
    // --- scan of cont -> pack dest / tail zero-fill dest ---
    int inclc = wave_scan(cont, lane);
    if (lane == 63) wsB[wv] = inclc;
    __syncthreads();
    int prec = 0, totc = 0;
#pragma unroll
    for (int i = 0; i < 4; ++i) { int t = wsB[i]; if (i < wv) prec += t; totc += t; }
    inclc += prec;                              // inclusive cont-count in [chunk, m]
    if (cont) {
      pdest_ws[idx] = carry_cont + inclc - 1;   // packed dest in [0, nnew)
    } else {
      int zr = m - (carry_cont + inclc);        // exclusive rank among non-cont
      pdest_ws[idx] = -(Mq - 1 - zr) - 1;       // zero-fill dest from the top
    }
    carry_run += tot;
    carry_cont += totc;
  }
}

// ---------------------------------------------------------------------------
// K3: bulk H-wide pass, single h-row read per slot. One block per slot (b,m):
//   out_wh[b,m,:] = live ? h[b,rank,:]*peff + wh[b,m,:]*(1-peff) : wh[b,m,:]
//   pd >= 0 : out_hp[b,pd,:]      = h[b,rank,:]   (continuing slot)
//   pd <  0 : out_hp[b,-(pd+1),:] = 0             (tail zero-fill, bijective)
// ---------------------------------------------------------------------------
__global__ __launch_bounds__(256) void k_apply(
    const float* __restrict__ h, const float* __restrict__ wh,
    const int* __restrict__ rank_ws, const float* __restrict__ peff_ws,
    const int* __restrict__ pdest_ws,
    float* __restrict__ out_hp, float* __restrict__ out_wh) {
  int bm = blockIdx.x;
  int b = bm >> 11;                             // M = 2048
  int tid = threadIdx.x;
  size_t rowoff = (size_t)bm * Hq;
  float4 w4 = ((const float4*)(wh + rowoff))[tid];
  int rk = rank_ws[bm];
  float4 a = make_float4(0.f, 0.f, 0.f, 0.f);
  float4 o;
  if (rk >= 0) {
    float pe = peff_ws[bm];
    a = ((const float4*)(h + ((size_t)(b * Mq + rk)) * Hq))[tid];
    float q = 1.0f - pe;
    o.x = a.x * pe + w4.x * q;
    o.y = a.y * pe + w4.y * q;
    o.z = a.z * pe + w4.z * q;
    o.w = a.w * pe + w4.w * q;
  } else {
    o = w4;                                     // dead row: peff==0
  }
  ((float4*)(out_wh + rowoff))[tid] = o;
  int pd = pdest_ws[bm];
  if (pd >= 0) {
    ((float4*)(out_hp + (((size_t)(b * Mq + pd)) * Hq)))[tid] = a;
  } else {
    int zd = -(pd + 1);
    ((float4*)(out_hp + (((size_t)(b * Mq + zd)) * Hq)))[tid] =
        make_float4(0.f, 0.f, 0.f, 0.f);
  }
}

// ---------------------------------------------------------------------------
extern "C" void kernel_launch(void* const* d_in, const int* in_sizes, int n_in,
                              void* d_out, int out_size, void* d_ws, size_t ws_size,
                              hipStream_t stream) {
  const float* h    = (const float*)d_in[0];
  const float* wh   = (const float*)d_in[1];
  const float* accp = (const float*)d_in[2];
  const float* rem  = (const float*)d_in[3];
  const float* pw   = (const float*)d_in[4];
  const float* pb   = (const float*)d_in[5];
  const int*   run  = (const int*)d_in[6];
  const int*   exin = (const int*)d_in[7];
  const int*   upd  = (const int*)d_in[8];

  float* out = (float*)d_out;
  const size_t BMH = (size_t)Bq * Mq * Hq;
  const size_t BM  = (size_t)Bq * Mq;
  float* out_hp   = out;
  float* out_wh   = out + BMH;
  float* out_acc  = out + 2 * BMH;
  float* out_rem  = out_acc + BM;
  float* out_run  = out_rem + BM;
  float* out_exit = out_run + BM;

  // workspace layout (all 4B elems): 4*BM + Bq ints ≈ 512 KB
  float* logits  = (float*)d_ws;
  int*   rank_ws = (int*)d_ws + BM;
  float* peff_ws = (float*)d_ws + 2 * BM;
  int*   pdest_ws= (int*)d_ws + 3 * BM;
  int*   nlive   = (int*)d_ws + 4 * BM;

  k_count<<<Bq, 256, 0, stream>>>(run, nlive);
  k_gemv<<<Bq * (Mq / 4), 256, 0, stream>>>(h, pw, pb, nlive, logits);
  k_scan<<<Bq, 256, 0, stream>>>(accp, rem, run, exin, upd, logits,
                                 out_acc, out_rem, out_run, out_exit,
                                 rank_ws, peff_ws, pdest_ws);
  k_apply<<<Bq * Mq, 256, 0, stream>>>(h, wh, rank_ws, peff_ws, pdest_ws,
                                       out_hp, out_wh);
}

// Round 7
// 462.459 us; speedup vs baseline: 1.0049x; 1.0049x over previous
//
#include <hip/hip_runtime.h>
#include <math.h>

#define Bq 16
#define Mq 2048
#define Hq 1024
#define BMQ (Bq * Mq)
static constexpr float THR = 0.99f;

typedef float f4v __attribute__((ext_vector_type(4)));

__device__ __forceinline__ void nt_store4(float* p, float x, float y, float z,
                                          float w) {
  f4v t = {x, y, z, w};
  __builtin_nontemporal_store(t, (f4v*)p);
}
__device__ __forceinline__ f4v nt_load4(const float* p) {
  return __builtin_nontemporal_load((const f4v*)p);
}

// ---------------------------------------------------------------------------
// K0: per-batch live-token count (nlive[b] = sum(run[b,:]))
// ---------------------------------------------------------------------------
__global__ __launch_bounds__(256) void k_count(const int* __restrict__ run,
                                               int* __restrict__ nlive) {
  int b = blockIdx.x;
  int tid = threadIdx.x;
  int s = 0;
  const int* r = run + b * Mq;
  for (int m = tid; m < Mq; m += 256) s += r[m];
#pragma unroll
  for (int off = 32; off; off >>= 1) s += __shfl_xor(s, off);
  __shared__ int ws4[4];
  if ((tid & 63) == 0) ws4[tid >> 6] = s;
  __syncthreads();
  if (tid == 0) nlive[b] = ws4[0] + ws4[1] + ws4[2] + ws4[3];
}

// ---------------------------------------------------------------------------
// K1: GEMV logits[b,r] = dot(h[b,r,:], p_weight) + p_bias for r < nlive[b]
// grid-strided, one wave per row, weight fragment register-hoisted per block
// ---------------------------------------------------------------------------
#define GRID_G 2048
__global__ __launch_bounds__(256) void k_gemv(const float* __restrict__ h,
                                              const float* __restrict__ pw,
                                              const float* __restrict__ pb,
                                              const int* __restrict__ nlive,
                                              float* __restrict__ logits) {
  int wv = threadIdx.x >> 6, lane = threadIdx.x & 63;
  const float4* w4 = (const float4*)pw;
  float4 w[4];
#pragma unroll
  for (int k = 0; k < 4; ++k) w[k] = w4[(k << 6) + lane];  // once per block
  float bias = pb[0];
  for (int task = blockIdx.x * 4 + wv; task < BMQ; task += GRID_G * 4) {
    int b = task >> 11;                       // M = 2048
    int r = task & (Mq - 1);
    if (r >= nlive[b]) continue;              // wave-uniform
    const float4* hrow = (const float4*)(h + ((size_t)task) * Hq);
    float s = 0.f;
#pragma unroll
    for (int k = 0; k < 4; ++k) {
      float4 a = hrow[(k << 6) + lane];       // coalesced: lane-contiguous
      s += a.x * w[k].x + a.y * w[k].y + a.z * w[k].z + a.w * w[k].w;
    }
#pragma unroll
    for (int off = 32; off; off >>= 1) s += __shfl_xor(s, off);
    if (lane == 0) logits[task] = s + bias;
  }
}

// ---------------------------------------------------------------------------
// K2: per-row prefix scans + all width-1 outputs + index tables.
// One block per batch row; 8 chunks of 256; wave-scan + LDS wave-sum combine.
// Per slot m:
//   rank_ws  = unpack source rank (-1 if dead)
//   peff_ws  = p_eff (reference arithmetic: exit -> 1-(accn-p))
//   pdest_ws = cdest >= 0    : continuing -> write h-row to packed col cdest
//              -(zd+1) < 0   : otherwise  -> zero-fill packed col zd
//   (cdest over cont slots covers [0,nnew); zd over the rest covers [nnew,M))
// ---------------------------------------------------------------------------
__device__ __forceinline__ int wave_scan(int v, int lane) {
#pragma unroll
  for (int off = 1; off < 64; off <<= 1) {
    int n = __shfl_up(v, off);
    if (lane >= off) v += n;
  }
  return v;
}

__global__ __launch_bounds__(256) void k_scan(
    const float* __restrict__ accp, const float* __restrict__ rem,
    const int* __restrict__ run, const int* __restrict__ exin,
    const int* __restrict__ upd, const float* __restrict__ logits,
    float* __restrict__ out_acc, float* __restrict__ out_rem,
    float* __restrict__ out_run, float* __restrict__ out_exit,
    int* __restrict__ rank_ws, float* __restrict__ peff_ws,
    int* __restrict__ pdest_ws) {
  int b = blockIdx.x;
  int tid = threadIdx.x;
  int lane = tid & 63, wv = tid >> 6;
  __shared__ int wsA[4], wsB[4];
  int carry_run = 0, carry_cont = 0;
  int unew = upd[0] + 1;
  for (int chunk = 0; chunk < Mq; chunk += 256) {
    int m = chunk + tid;
    int idx = b * Mq + m;
    int r = run[idx];
    // --- scan of run -> unpack source rank ---
    int incl = wave_scan(r, lane);
    if (lane == 63) wsA[wv] = incl;
    __syncthreads();
    int pre = 0, tot = 0;
#pragma unroll
    for (int i = 0; i < 4; ++i) { int t = wsA[i]; if (i < wv) pre += t; tot += t; }
    incl += pre;
    int rank = carry_run + incl - 1;            // valid only when r
    // --- per-slot math ---
    float p = 0.f;
    if (r) {
      float z = logits[b * Mq + rank];
      if (z >= 0.f) p = 1.f / (1.f + expf(-z));      // stable sigmoid,
      else { float e = expf(z); p = e / (1.f + e); } // matches jax.nn.sigmoid
    }
    float accn = accp[idx] + p;
    int cont = (int)(accn < THR) & r;
    int ex = r & (cont ^ 1);
    float diff = accn - p;                      // keep reference rounding
    float peff = cont ? p : (ex ? (1.0f - diff) : 0.0f);
    out_acc[idx] = accn;
    out_rem[idx] = rem[idx] + (ex ? peff : 0.0f);
    out_run[idx] = cont ? 1.0f : 0.0f;
    out_exit[idx] = (float)(exin[idx] + (ex ? unew : 0));
    rank_ws[idx] = r ? rank : -1;
    peff_ws[idx] = peff;
    // --- scan of cont -> pack dest / tail zero-fill dest ---
    int inclc = wave_scan(cont, lane);
    if (lane == 63) wsB[wv] = inclc;
    __syncthreads();
    int prec = 0, totc = 0;
#pragma unroll
    for (int i = 0; i < 4; ++i) { int t = wsB[i]; if (i < wv) prec += t; totc += t; }
    inclc += prec;                              // inclusive cont-count in [chunk, m]
    if (cont) {
      pdest_ws[idx] = carry_cont + inclc - 1;   // packed dest in [0, nnew)
    } else {
      int zr = m - (carry_cont + inclc);        // exclusive rank among non-cont
      pdest_ws[idx] = -(Mq - 1 - zr) - 1;       // zero-fill dest from the top
    }
    carry_run += tot;
    carry_cont += totc;
  }
}

// ---------------------------------------------------------------------------
// K3: bulk H-wide pass, single h-row read per slot, grid-strided (16 tasks
// per block). Non-temporal stores for all H-wide outputs; NT load for wh.
//   out_wh[b,m,:] = live ? h[b,rank,:]*peff + wh[b,m,:]*(1-peff) : wh[b,m,:]
//   pd >= 0 : out_hp[b,pd,:]      = h[b,rank,:]   (continuing slot)
//   pd <  0 : out_hp[b,-(pd+1),:] = 0             (tail zero-fill, bijective)
// ---------------------------------------------------------------------------
#define GRID_A 2048
__global__ __launch_bounds__(256) void k_apply(
    const float* __restrict__ h, const float* __restrict__ wh,
    const int* __restrict__ rank_ws, const float* __restrict__ peff_ws,
    const int* __restrict__ pdest_ws,
    float* __restrict__ out_hp, float* __restrict__ out_wh) {
  int tid = threadIdx.x;
  for (int bm = blockIdx.x; bm < BMQ; bm += GRID_A) {
    int b = bm >> 11;                           // M = 2048
    size_t rowoff = (size_t)bm * Hq;
    int rk = rank_ws[bm];                       // independent scalar loads
    int pd = pdest_ws[bm];
    float pe = peff_ws[bm];
    f4v w4 = nt_load4(wh + rowoff + 4 * tid);
    float ax = 0.f, ay = 0.f, az = 0.f, aw = 0.f;
    float ox, oy, oz, ow;
    if (rk >= 0) {
      const float4* hrow = (const float4*)(h + ((size_t)(b * Mq + rk)) * Hq);
      float4 a = hrow[tid];
      ax = a.x; ay = a.y; az = a.z; aw = a.w;
      float q = 1.0f - pe;
      ox = ax * pe + w4.x * q;
      oy = ay * pe + w4.y * q;
      oz = az * pe + w4.z * q;
      ow = aw * pe + w4.w * q;
    } else {
      ox = w4.x; oy = w4.y; oz = w4.z; ow = w4.w;  // dead row: peff==0
    }
    nt_store4(out_wh + rowoff + 4 * tid, ox, oy, oz, ow);
    if (pd >= 0) {
      nt_store4(out_hp + (((size_t)(b * Mq + pd)) * Hq) + 4 * tid, ax, ay, az, aw);
    } else {
      int zd = -(pd + 1);
      nt_store4(out_hp + (((size_t)(b * Mq + zd)) * Hq) + 4 * tid, 0.f, 0.f, 0.f,
                0.f);
    }
  }
}

// ---------------------------------------------------------------------------
extern "C" void kernel_launch(void* const* d_in, const int* in_sizes, int n_in,
                              void* d_out, int out_size, void* d_ws, size_t ws_size,
                              hipStream_t stream) {
  const float* h    = (const float*)d_in[0];
  const float* wh   = (const float*)d_in[1];
  const float* accp = (const float*)d_in[2];
  const float* rem  = (const float*)d_in[3];
  const float* pw   = (const float*)d_in[4];
  const float* pb   = (const float*)d_in[5];
  const int*   run  = (const int*)d_in[6];
  const int*   exin = (const int*)d_in[7];
  const int*   upd  = (const int*)d_in[8];

  float* out = (float*)d_out;
  const size_t BMH = (size_t)Bq * Mq * Hq;
  const size_t BM  = (size_t)Bq * Mq;
  float* out_hp   = out;
  float* out_wh   = out + BMH;
  float* out_acc  = out + 2 * BMH;
  float* out_rem  = out_acc + BM;
  float* out_run  = out_rem + BM;
  float* out_exit = out_run + BM;

  // workspace layout (all 4B elems): 4*BM + Bq ints ≈ 512 KB
  float* logits  = (float*)d_ws;
  int*   rank_ws = (int*)d_ws + BM;
  float* peff_ws = (float*)d_ws + 2 * BM;
  int*   pdest_ws= (int*)d_ws + 3 * BM;
  int*   nlive   = (int*)d_ws + 4 * BM;

  k_count<<<Bq, 256, 0, stream>>>(run, nlive);
  k_gemv<<<GRID_G, 256, 0, stream>>>(h, pw, pb, nlive, logits);
  k_scan<<<Bq, 256, 0, stream>>>(accp, rem, run, exin, upd, logits,
                                 out_acc, out_rem, out_run, out_exit,
                                 rank_ws, peff_ws, pdest_ws);
  k_apply<<<GRID_A, 256, 0, stream>>>(h, wh, rank_ws, peff_ws, pdest_ws,
                                      out_hp, out_wh);
}

// Round 8
// 444.632 us; speedup vs baseline: 1.0452x; 1.0401x over previous
//
#include <hip/hip_runtime.h>
#include <math.h>

#define Bq 16
#define Mq 2048
#define Hq 1024
#define BMQ (Bq * Mq)
static constexpr float THR = 0.99f;

typedef float f4v __attribute__((ext_vector_type(4)));

__device__ __forceinline__ void nt_store4(float* p, float x, float y, float z,
                                          float w) {
  f4v t = {x, y, z, w};
  __builtin_nontemporal_store(t, (f4v*)p);
}
__device__ __forceinline__ f4v nt_load4(const float* p) {
  return __builtin_nontemporal_load((const f4v*)p);
}

// ---------------------------------------------------------------------------
// K1: GEMV logits[b,r] = dot(h[b,r,:], p_weight) + p_bias for r < nlive[b].
// k_count is folded in: each block counts nlive for the 4 batch rows it
// touches (iter i handles b = blockIdx>>9 + 4i). run rows are L2-resident
// after the first block touches them (128 KB unique).
// ---------------------------------------------------------------------------
#define GRID_G 2048
__global__ __launch_bounds__(256) void k_gemv(const float* __restrict__ h,
                                              const float* __restrict__ pw,
                                              const float* __restrict__ pb,
                                              const int* __restrict__ run,
                                              float* __restrict__ logits) {
  int wv = threadIdx.x >> 6, lane = threadIdx.x & 63;
  int b0 = blockIdx.x >> 9;                    // base batch row (0..3)
  __shared__ int s_nl[4];
  // wave wv counts live slots of row (b0 + 4*wv)
  {
    const int* rr = run + (b0 + 4 * wv) * Mq;
    int c = 0;
#pragma unroll
    for (int i = 0; i < Mq / 64; ++i) c += rr[(i << 6) + lane];
#pragma unroll
    for (int off = 32; off; off >>= 1) c += __shfl_xor(c, off);
    if (lane == 0) s_nl[wv] = c;
  }
  const float4* w4 = (const float4*)pw;
  float4 w[4];
#pragma unroll
  for (int k = 0; k < 4; ++k) w[k] = w4[(k << 6) + lane];  // once per block
  float bias = pb[0];
  __syncthreads();
#pragma unroll
  for (int i = 0; i < 4; ++i) {
    int task = (blockIdx.x << 2) + wv + (i << 13);  // b = b0 + 4i
    int r = task & (Mq - 1);
    if (r < s_nl[i]) {
      const float4* hrow = (const float4*)(h + ((size_t)task) * Hq);
      float s = 0.f;
#pragma unroll
      for (int k = 0; k < 4; ++k) {
        float4 a = hrow[(k << 6) + lane];      // coalesced: lane-contiguous
        s += a.x * w[k].x + a.y * w[k].y + a.z * w[k].z + a.w * w[k].w;
      }
#pragma unroll
      for (int off = 32; off; off >>= 1) s += __shfl_xor(s, off);
      if (lane == 0) logits[task] = s + bias;
    }
  }
}

// ---------------------------------------------------------------------------
// K2: per-row prefix scans + all width-1 outputs + index tables.
// One 1024-thread block per batch row; 2 chunks; wave-scan + 16-wave LDS
// combine (4 barriers total vs 16 at 256 threads -> lower latency).
// Per slot m:
//   rank_ws  = unpack source rank (-1 if dead)
//   peff_ws  = p_eff (reference arithmetic: exit -> 1-(accn-p))
//   pdest_ws = cdest >= 0  : continuing -> write h-row to packed col cdest
//              -(zd+1) < 0 : otherwise  -> zero-fill packed col zd
//   (cdest over cont slots covers [0,nnew); zd over the rest covers [nnew,M))
// ---------------------------------------------------------------------------
#define SCAN_T 1024
__device__ __forceinline__ int wave_scan(int v, int lane) {
#pragma unroll
  for (int off = 1; off < 64; off <<= 1) {
    int n = __shfl_up(v, off);
    if (lane >= off) v += n;
  }
  return v;
}

__global__ __launch_bounds__(SCAN_T) void k_scan(
    const float* __restrict__ accp, const float* __restrict__ rem,
    const int* __restrict__ run, const int* __restrict__ exin,
    const int* __restrict__ upd, const float* __restrict__ logits,
    float* __restrict__ out_acc, float* __restrict__ out_rem,
    float* __restrict__ out_run, float* __restrict__ out_exit,
    int* __restrict__ rank_ws, float* __restrict__ peff_ws,
    int* __restrict__ pdest_ws) {
  int b = blockIdx.x;
  int tid = threadIdx.x;
  int lane = tid & 63, wv = tid >> 6;          // wv in [0,16)
  __shared__ int wsA[16], wsB[16];
  int carry_run = 0, carry_cont = 0;
  int unew = upd[0] + 1;
  for (int chunk = 0; chunk < Mq; chunk += SCAN_T) {
    int m = chunk + tid;
    int idx = b * Mq + m;
    int r = run[idx];
    // --- scan of run -> unpack source rank ---
    int incl = wave_scan(r, lane);
    if (lane == 63) wsA[wv] = incl;
    __syncthreads();
    int pre = 0, tot = 0;
#pragma unroll
    for (int i = 0; i < 16; ++i) { int t = wsA[i]; if (i < wv) pre += t; tot += t; }
    incl += pre;
    int rank = carry_run + incl - 1;            // valid only when r
    // --- per-slot math ---
    float p = 0.f;
    if (r) {
      float z = logits[b * Mq + rank];
      if (z >= 0.f) p = 1.f / (1.f + expf(-z));      // stable sigmoid,
      else { float e = expf(z); p = e / (1.f + e); } // matches jax.nn.sigmoid
    }
    float accn = accp[idx] + p;
    int cont = (int)(accn < THR) & r;
    int ex = r & (cont ^ 1);
    float diff = accn - p;                      // keep reference rounding
    float peff = cont ? p : (ex ? (1.0f - diff) : 0.0f);
    out_acc[idx] = accn;
    out_rem[idx] = rem[idx] + (ex ? peff : 0.0f);
    out_run[idx] = cont ? 1.0f : 0.0f;
    out_exit[idx] = (float)(exin[idx] + (ex ? unew : 0));
    rank_ws[idx] = r ? rank : -1;
    peff_ws[idx] = peff;
    // --- scan of cont -> pack dest / tail zero-fill dest ---
    int inclc = wave_scan(cont, lane);
    if (lane == 63) wsB[wv] = inclc;
    __syncthreads();
    int prec = 0, totc = 0;
#pragma unroll
    for (int i = 0; i < 16; ++i) { int t = wsB[i]; if (i < wv) prec += t; totc += t; }
    inclc += prec;                              // inclusive cont-count in [chunk, m]
    if (cont) {
      pdest_ws[idx] = carry_cont + inclc - 1;   // packed dest in [0, nnew)
    } else {
      int zr = m - (carry_cont + inclc);        // exclusive rank among non-cont
      pdest_ws[idx] = -(Mq - 1 - zr) - 1;       // zero-fill dest from the top
    }
    carry_run += tot;
    carry_cont += totc;
  }
}

// ---------------------------------------------------------------------------
// K3: bulk H-wide pass, single h-row read per slot, grid-strided (16 tasks
// per block). Non-temporal stores for all H-wide outputs; NT load for wh
// (read-once streams); h gather stays cacheable (L3 reuse from k_gemv).
//   out_wh[b,m,:] = live ? h[b,rank,:]*peff + wh[b,m,:]*(1-peff) : wh[b,m,:]
//   pd >= 0 : out_hp[b,pd,:]      = h[b,rank,:]   (continuing slot)
//   pd <  0 : out_hp[b,-(pd+1),:] = 0             (tail zero-fill, bijective)
// rank/pdest are monotone in m, so gathers and pack-writes are near-sequential.
// ---------------------------------------------------------------------------
#define GRID_A 2048
__global__ __launch_bounds__(256) void k_apply(
    const float* __restrict__ h, const float* __restrict__ wh,
    const int* __restrict__ rank_ws, const float* __restrict__ peff_ws,
    const int* __restrict__ pdest_ws,
    float* __restrict__ out_hp, float* __restrict__ out_wh) {
  int tid = threadIdx.x;
  for (int bm = blockIdx.x; bm < BMQ; bm += GRID_A) {
    int b = bm >> 11;                           // M = 2048
    size_t rowoff = (size_t)bm * Hq;
    int rk = rank_ws[bm];                       // independent scalar loads
    int pd = pdest_ws[bm];
    float pe = peff_ws[bm];
    f4v w4 = nt_load4(wh + rowoff + 4 * tid);
    float ax = 0.f, ay = 0.f, az = 0.f, aw = 0.f;
    float ox, oy, oz, ow;
    if (rk >= 0) {
      const float4* hrow = (const float4*)(h + ((size_t)(b * Mq + rk)) * Hq);
      float4 a = hrow[tid];
      ax = a.x; ay = a.y; az = a.z; aw = a.w;
      float q = 1.0f - pe;
      ox = ax * pe + w4.x * q;
      oy = ay * pe + w4.y * q;
      oz = az * pe + w4.z * q;
      ow = aw * pe + w4.w * q;
    } else {
      ox = w4.x; oy = w4.y; oz = w4.z; ow = w4.w;  // dead row: peff==0
    }
    nt_store4(out_wh + rowoff + 4 * tid, ox, oy, oz, ow);
    if (pd >= 0) {
      nt_store4(out_hp + (((size_t)(b * Mq + pd)) * Hq) + 4 * tid, ax, ay, az, aw);
    } else {
      int zd = -(pd + 1);
      nt_store4(out_hp + (((size_t)(b * Mq + zd)) * Hq) + 4 * tid, 0.f, 0.f, 0.f,
                0.f);
    }
  }
}

// ---------------------------------------------------------------------------
extern "C" void kernel_launch(void* const* d_in, const int* in_sizes, int n_in,
                              void* d_out, int out_size, void* d_ws, size_t ws_size,
                              hipStream_t stream) {
  const float* h    = (const float*)d_in[0];
  const float* wh   = (const float*)d_in[1];
  const float* accp = (const float*)d_in[2];
  const float* rem  = (const float*)d_in[3];
  const float* pw   = (const float*)d_in[4];
  const float* pb   = (const float*)d_in[5];
  const int*   run  = (const int*)d_in[6];
  const int*   exin = (const int*)d_in[7];
  const int*   upd  = (const int*)d_in[8];

  float* out = (float*)d_out;
  const size_t BMH = (size_t)Bq * Mq * Hq;
  const size_t BM  = (size_t)Bq * Mq;
  float* out_hp   = out;
  float* out_wh   = out + BMH;
  float* out_acc  = out + 2 * BMH;
  float* out_rem  = out_acc + BM;
  float* out_run  = out_rem + BM;
  float* out_exit = out_run + BM;

  // workspace layout (all 4B elems): 4*BM ≈ 512 KB
  float* logits  = (float*)d_ws;
  int*   rank_ws = (int*)d_ws + BM;
  float* peff_ws = (float*)d_ws + 2 * BM;
  int*   pdest_ws= (int*)d_ws + 3 * BM;

  k_gemv<<<GRID_G, 256, 0, stream>>>(h, pw, pb, run, logits);
  k_scan<<<Bq, SCAN_T, 0, stream>>>(accp, rem, run, exin, upd, logits,
                                    out_acc, out_rem, out_run, out_exit,
                                    rank_ws, peff_ws, pdest_ws);
  k_apply<<<GRID_A, 256, 0, stream>>>(h, wh, rank_ws, peff_ws, pdest_ws,
                                      out_hp, out_wh);
}